// Round 3
// baseline (1313.385 us; speedup 1.0000x reference)
//
#include <hip/hip_runtime.h>
#include <math.h>

#define S_LEN 2048
#define T_LEN 4095
#define NH 12
#define DEPTH 64
#define DM 768

// ---- workspace layout (in floats) ----  (pe lives in d_out's attn region)
// qh/kh/vh: [12][2048][64] head-major
// rk:       [12][4095][64] head-major
// oh:       [2048][768]
// gmax:     1 float
#define QH_OFF  ((size_t)0)
#define KH_OFF  (QH_OFF + (size_t)NH*S_LEN*DEPTH)
#define VH_OFF  (KH_OFF + (size_t)NH*S_LEN*DEPTH)
#define RK_OFF  (VH_OFF + (size_t)NH*S_LEN*DEPTH)
#define OH_OFF  (RK_OFF + (size_t)NH*T_LEN*DEPTH)
#define GMAX_OFF (OH_OFF + (size_t)S_LEN*DM)
#define WS_NEEDED_BYTES ((GMAX_OFF + 16) * sizeof(float))

__global__ void init_gmax(float* g) { *g = 0.0f; }

__global__ void ws_too_small(float* out, float wsz) { out[0] = wsz; }

// ---------------- positional features ----------------
// one block per position t (0..4094), 128 threads = feature index
__global__ __launch_bounds__(128) void pe_kernel(float* __restrict__ pe, float* __restrict__ gmax)
{
    int t = blockIdx.x;
    int f = threadIdx.x;
    float pos  = (float)(t - (S_LEN - 1));
    float apos = fabsf(pos);
    float sgn  = (pos > 0.f) ? 1.f : ((pos < 0.f) ? -1.f : 0.f);

    // exponential basis: half_life = 2^linspace(3, 11, 128); exp(-ln2/hl * apos) = 2^(-apos/hl)
    double hl = exp2(3.0 + 8.0 * (double)f / 127.0);
    float e1 = (float)exp2(-(double)apos / hl);

    // central mask: cw = 2^(f+1) - 1
    double cw = exp2((double)(f + 1)) - 1.0;
    float cm = (cw > (double)apos) ? 1.f : 0.f;

    // gamma pdf basis (f64: the exponent has ~1e5-magnitude cancellation)
    // mean = 16*(f+1), stdv = 8 -> conc = 4*(f+1)^2, rate = (f+1)/4
    double fp1 = (double)(f + 1);
    double conc = 4.0 * fp1 * fp1;
    double rate = 0.25 * fp1;
    double prob = 0.0;
    if (apos != 0.f) {
        double la = log((double)apos);
        double lu = (conc - 1.0) * la - rate * (double)apos;
        double ln = lgamma(conc) - conc * log(rate);
        prob = exp(lu - ln);
    }
    float pr = (float)prob;

    float* row = pe + (size_t)t * DM;
    row[f]        = e1;
    row[128 + f]  = e1 * sgn;
    row[256 + f]  = cm;
    row[384 + f]  = cm * sgn;
    row[512 + f]  = pr;        // unnormalized; scaled by 1/gmax later
    row[640 + f]  = pr * sgn;

    __shared__ float red[128];
    red[f] = pr;
    __syncthreads();
    for (int s = 64; s > 0; s >>= 1) {
        if (f < s) red[f] = fmaxf(red[f], red[f + s]);
        __syncthreads();
    }
    if (f == 0) atomicMax((int*)gmax, __float_as_int(red[0]));
}

__global__ __launch_bounds__(256) void pe_scale(float* __restrict__ pe, const float* __restrict__ gmax)
{
    float inv = 1.0f / (*gmax);
    int t = blockIdx.x;
    int c = threadIdx.x;           // 0..255 -> columns 512..767
    pe[(size_t)t * DM + 512 + c] *= inv;
}

// ---------------- generic fp32 GEMM: C = A[M,768] @ W[768,768] ----------------
// mode 0: head-scatter  dst[((n>>6)*M + m)*64 + (n&63)] = alpha*acc
// mode 1: row-major + bias: dst[m*768+n] = acc + bias[n]
__global__ __launch_bounds__(256) void gemm64(const float* __restrict__ A, const float* __restrict__ W,
                                              float* __restrict__ C, int M, float alpha, int mode,
                                              const float* __restrict__ bias)
{
    const int K = DM, N = DM;
    __shared__ float As[64][17];
    __shared__ float Ws[16][68];
    int tid = threadIdx.x;
    int row0 = blockIdx.x * 64, col0 = blockIdx.y * 64;
    int ty = tid >> 4, tx = tid & 15;

    float acc[4][4];
    #pragma unroll
    for (int i = 0; i < 4; ++i)
        #pragma unroll
        for (int j = 0; j < 4; ++j) acc[i][j] = 0.f;

    for (int k0 = 0; k0 < K; k0 += 16) {
        {
            int r = tid >> 2;
            int kc = (tid & 3) * 4;
            int gr = row0 + r;
            float4 v = make_float4(0, 0, 0, 0);
            if (gr < M) v = *(const float4*)&A[(size_t)gr * K + k0 + kc];
            As[r][kc] = v.x; As[r][kc + 1] = v.y; As[r][kc + 2] = v.z; As[r][kc + 3] = v.w;
        }
        {
            int r = tid >> 4;
            int c = (tid & 15) * 4;
            float4 v = *(const float4*)&W[(size_t)(k0 + r) * N + col0 + c];
            Ws[r][c] = v.x; Ws[r][c + 1] = v.y; Ws[r][c + 2] = v.z; Ws[r][c + 3] = v.w;
        }
        __syncthreads();
        #pragma unroll
        for (int kk = 0; kk < 16; ++kk) {
            float a[4], b[4];
            #pragma unroll
            for (int i = 0; i < 4; ++i) a[i] = As[ty * 4 + i][kk];
            #pragma unroll
            for (int j = 0; j < 4; ++j) b[j] = Ws[kk][tx * 4 + j];
            #pragma unroll
            for (int i = 0; i < 4; ++i)
                #pragma unroll
                for (int j = 0; j < 4; ++j) acc[i][j] = fmaf(a[i], b[j], acc[i][j]);
        }
        __syncthreads();
    }

    #pragma unroll
    for (int i = 0; i < 4; ++i) {
        int m = row0 + ty * 4 + i;
        if (m >= M) continue;
        #pragma unroll
        for (int j = 0; j < 4; ++j) {
            int n = col0 + tx * 4 + j;
            float v = acc[i][j];
            if (mode == 0) {
                int hh = n >> 6, d = n & 63;
                C[((size_t)hh * M + m) * 64 + d] = v * alpha;
            } else {
                C[(size_t)m * N + n] = v + bias[n];
            }
        }
    }
}

// ---------------- fused attention ----------------
// block: (i-tile of 32 rows, head). 256 threads.
// phase 1: logits (content + shifted rel) -> raw logits to global attn, online max/sum
// phase 2: normalize+write attn, accumulate PV, write out_heads
#define TM 32
#define TN 64

__global__ __launch_bounds__(256) void attn_fused(
    const float* __restrict__ qh, const float* __restrict__ kh, const float* __restrict__ vh,
    const float* __restrict__ rk, const float* __restrict__ rw, const float* __restrict__ rr,
    float* __restrict__ attn, float* __restrict__ oh)
{
    __shared__ __align__(16) float smem[15232];
    // qw: [32][68] @0 ; qr: [32][68] @2176 ; kv: [64][68] @4352 ; rk: [96][68] @8704 ; p aliases rk
#define QW_(r,c)  smem[(r)*68 + (c)]
#define QR_(r,c)  smem[2176 + (r)*68 + (c)]
#define KV_(r,c)  smem[4352 + (r)*68 + (c)]
#define RKS_(r,c) smem[8704 + (r)*68 + (c)]
#define PS_(r,c)  smem[8704 + (r)*68 + (c)]

    int h = blockIdx.y;
    int i0 = blockIdx.x * TM;
    int tid = threadIdx.x;

    const float* kh_h = kh + (size_t)h * S_LEN * DEPTH;
    const float* rk_h = rk + (size_t)h * T_LEN * DEPTH;
    const float* vh_h = vh + (size_t)h * S_LEN * DEPTH;
    float* attn_h = attn + ((size_t)h * S_LEN + i0) * S_LEN;

    // stage q rows (+r_w / +r_r)
    for (int idx = tid; idx < TM * DEPTH; idx += 256) {
        int r = idx >> 6, d = idx & 63;
        float qv = qh[((size_t)h * S_LEN + (i0 + r)) * DEPTH + d];
        QW_(r, d) = qv + rw[h * 64 + d];
        QR_(r, d) = qv + rr[h * 64 + d];
    }

    int il = tid >> 3;        // query row in tile, 0..31
    int jb = tid & 7;         // j offset; this thread handles j_loc = jb + 8*jj
    float run_max = -3.0e38f, run_sum = 0.f;

    for (int jt = 0; jt < S_LEN; jt += TN) {
        __syncthreads();
        // stage kh tile [64][64]
        for (int idx = tid; idx < TN * 16; idx += 256) {
            int r = idx >> 4, c4 = (idx & 15) << 2;
            float4 v = *(const float4*)&kh_h[(size_t)(jt + r) * DEPTH + c4];
            *(float4*)&KV_(r, c4) = v;
        }
        // stage rk window [96][64]; t = 2047 + (jt+jl) - (i0+il) -> local r = jl - il + 31
        int tbase = (S_LEN - 1) + jt - i0 - (TM - 1);
        for (int idx = tid; idx < 96 * 16; idx += 256) {
            int r = idx >> 4, c4 = (idx & 15) << 2;
            int t = tbase + r;
            float4 v = make_float4(0, 0, 0, 0);
            if (t >= 0 && t < T_LEN) v = *(const float4*)&rk_h[(size_t)t * DEPTH + c4];
            *(float4*)&RKS_(r, c4) = v;
        }
        __syncthreads();

        float acc[8] = {0, 0, 0, 0, 0, 0, 0, 0};
        #pragma unroll
        for (int kk = 0; kk < DEPTH; kk += 4) {
            float4 qwv = *(const float4*)&QW_(il, kk);
            float4 qrv = *(const float4*)&QR_(il, kk);
            #pragma unroll
            for (int jj = 0; jj < 8; ++jj) {
                int jl = jb + (jj << 3);
                float4 khv = *(const float4*)&KV_(jl, kk);
                float4 rkv = *(const float4*)&RKS_(jl + (TM - 1) - il, kk);
                acc[jj] += qwv.x * khv.x + qwv.y * khv.y + qwv.z * khv.z + qwv.w * khv.w
                         + qrv.x * rkv.x + qrv.y * rkv.y + qrv.z * rkv.z + qrv.w * rkv.w;
            }
        }
        // write raw logits + online max/sum
        float tmax = -3.0e38f;
        #pragma unroll
        for (int jj = 0; jj < 8; ++jj) {
            attn_h[(size_t)il * S_LEN + jt + jb + (jj << 3)] = acc[jj];
            tmax = fmaxf(tmax, acc[jj]);
        }
        tmax = fmaxf(tmax, __shfl_xor(tmax, 1));
        tmax = fmaxf(tmax, __shfl_xor(tmax, 2));
        tmax = fmaxf(tmax, __shfl_xor(tmax, 4));
        float nmax = fmaxf(run_max, tmax);
        float tsum = 0.f;
        #pragma unroll
        for (int jj = 0; jj < 8; ++jj) tsum += expf(acc[jj] - nmax);
        tsum += __shfl_xor(tsum, 1);
        tsum += __shfl_xor(tsum, 2);
        tsum += __shfl_xor(tsum, 4);
        run_sum = run_sum * expf(run_max - nmax) + tsum;
        run_max = nmax;
    }

    // phase 2: normalize + PV
    float inv_sum = 1.0f / run_sum;
    int db = (tid & 7) << 3;     // output d-block for PV
    float pv[8] = {0, 0, 0, 0, 0, 0, 0, 0};

    for (int jt = 0; jt < S_LEN; jt += TN) {
        __syncthreads();
        // stage vh tile into kv buffer
        for (int idx = tid; idx < TN * 16; idx += 256) {
            int r = idx >> 4, c4 = (idx & 15) << 2;
            float4 v = *(const float4*)&vh_h[(size_t)(jt + r) * DEPTH + c4];
            *(float4*)&KV_(r, c4) = v;
        }
        // normalize this thread's logits (written by this same thread in phase 1)
        #pragma unroll
        for (int jj = 0; jj < 8; ++jj) {
            int jcol = jb + (jj << 3);
            size_t gi = (size_t)il * S_LEN + jt + jcol;
            float l = attn_h[gi];
            float p = expf(l - run_max) * inv_sum;
            attn_h[gi] = p;
            PS_(il, jcol) = p;
        }
        __syncthreads();
        #pragma unroll 4
        for (int jl = 0; jl < TN; ++jl) {
            float pval = PS_(il, jl);
            float4 v0 = *(const float4*)&KV_(jl, db);
            float4 v1 = *(const float4*)&KV_(jl, db + 4);
            pv[0] = fmaf(pval, v0.x, pv[0]);
            pv[1] = fmaf(pval, v0.y, pv[1]);
            pv[2] = fmaf(pval, v0.z, pv[2]);
            pv[3] = fmaf(pval, v0.w, pv[3]);
            pv[4] = fmaf(pval, v1.x, pv[4]);
            pv[5] = fmaf(pval, v1.y, pv[5]);
            pv[6] = fmaf(pval, v1.z, pv[6]);
            pv[7] = fmaf(pval, v1.w, pv[7]);
        }
    }

    int m = i0 + il;
    *(float4*)&oh[(size_t)m * DM + h * 64 + db]     = make_float4(pv[0], pv[1], pv[2], pv[3]);
    *(float4*)&oh[(size_t)m * DM + h * 64 + db + 4] = make_float4(pv[4], pv[5], pv[6], pv[7]);
#undef QW_
#undef QR_
#undef KV_
#undef RKS_
#undef PS_
}

extern "C" void kernel_launch(void* const* d_in, const int* in_sizes, int n_in,
                              void* d_out, int out_size, void* d_ws, size_t ws_size,
                              hipStream_t stream) {
    const float* q    = (const float*)d_in[0];
    const float* k    = (const float*)d_in[1];
    const float* v    = (const float*)d_in[2];
    const float* wq   = (const float*)d_in[3];
    const float* wk   = (const float*)d_in[4];
    const float* wv   = (const float*)d_in[5];
    const float* w_rk = (const float*)d_in[6];
    const float* r_w  = (const float*)d_in[7];
    const float* r_r  = (const float*)d_in[8];
    const float* w_out= (const float*)d_in[9];
    const float* b_out= (const float*)d_in[10];

    float* outp = (float*)d_out;                       // [2048][768]
    float* attn = outp + (size_t)S_LEN * DM;           // [12][2048][2048]

    // Diagnostic fallback: if the workspace is too small, report its size via out[0]
    // (absmax then ~= ws_size) instead of faulting.
    if (ws_size < WS_NEEDED_BYTES) {
        hipLaunchKernelGGL(ws_too_small, dim3(1), dim3(1), 0, stream, outp, (float)ws_size);
        return;
    }

    float* ws = (float*)d_ws;
    float* qh = ws + QH_OFF;
    float* kh = ws + KH_OFF;
    float* vh = ws + VH_OFF;
    float* rk = ws + RK_OFF;
    float* oh = ws + OH_OFF;
    float* gmax = ws + GMAX_OFF;
    float* pe = attn;                                  // [4095][768] — dead before attn_fused writes attn

    hipLaunchKernelGGL(init_gmax, dim3(1), dim3(1), 0, stream, gmax);

    // projections (head-scatter). qh scaled by 1/sqrt(64)
    hipLaunchKernelGGL(gemm64, dim3(32, 12), dim3(256), 0, stream, q, wq, qh, S_LEN, 0.125f, 0, (const float*)nullptr);
    hipLaunchKernelGGL(gemm64, dim3(32, 12), dim3(256), 0, stream, k, wk, kh, S_LEN, 1.0f, 0, (const float*)nullptr);
    hipLaunchKernelGGL(gemm64, dim3(32, 12), dim3(256), 0, stream, v, wv, vh, S_LEN, 1.0f, 0, (const float*)nullptr);

    // positional features
    hipLaunchKernelGGL(pe_kernel, dim3(T_LEN), dim3(128), 0, stream, pe, gmax);
    hipLaunchKernelGGL(pe_scale, dim3(T_LEN), dim3(256), 0, stream, pe, gmax);

    // rk = pe @ w_rk (head-scatter, M=4095)
    hipLaunchKernelGGL(gemm64, dim3(64, 12), dim3(256), 0, stream, pe, w_rk, rk, T_LEN, 1.0f, 0, (const float*)nullptr);

    // fused attention
    hipLaunchKernelGGL(attn_fused, dim3(S_LEN / TM, NH), dim3(256), 0, stream,
                       qh, kh, vh, rk, r_w, r_r, attn, oh);

    // output projection + bias
    hipLaunchKernelGGL(gemm64, dim3(32, 12), dim3(256), 0, stream, oh, w_out, outp, S_LEN, 1.0f, 1, b_out);
}

// Round 4
// 879.241 us; speedup vs baseline: 1.4938x; 1.4938x over previous
//
#include <hip/hip_runtime.h>
#include <math.h>

#define S_LEN 2048
#define T_LEN 4095
#define NH 12
#define DEPTH 64
#define DM 768

typedef unsigned short u16;
typedef u16   u16x4 __attribute__((ext_vector_type(4)));
typedef short s16x8 __attribute__((ext_vector_type(8)));   // 8 bf16 (4 VGPRs) MFMA frag
typedef float f32x4 __attribute__((ext_vector_type(4)));   // MFMA accumulator

// ---- workspace layout (float-granular offsets; qh/kh/vh/rk stored as bf16 inside) ----
#define QH_OFF  ((size_t)0)
#define KH_OFF  (QH_OFF + (size_t)NH*S_LEN*DEPTH)
#define VH_OFF  (KH_OFF + (size_t)NH*S_LEN*DEPTH)
#define RK_OFF  (VH_OFF + (size_t)NH*S_LEN*DEPTH)
#define OH_OFF  (RK_OFF + (size_t)NH*T_LEN*DEPTH)
#define GMAX_OFF (OH_OFF + (size_t)S_LEN*DM)
#define WS_NEEDED_BYTES ((GMAX_OFF + 16) * sizeof(float))

__device__ __forceinline__ float bf2f(u16 x) {
    union { unsigned u; float f; } c; c.u = ((unsigned)x) << 16; return c.f;
}
__device__ __forceinline__ u16 f2bf(float f) {
    union { float f; unsigned u; } c; c.f = f;
    unsigned u = c.u;
    return (u16)((u + 0x7FFFu + ((u >> 16) & 1u)) >> 16);
}

__global__ void init_gmax(float* g) { *g = 0.0f; }
__global__ void ws_too_small(float* out, float wsz) { out[0] = wsz; }

// ---------------- positional features ----------------
__global__ __launch_bounds__(128) void pe_kernel(float* __restrict__ pe, float* __restrict__ gmax)
{
    int t = blockIdx.x;
    int f = threadIdx.x;
    float pos  = (float)(t - (S_LEN - 1));
    float apos = fabsf(pos);
    float sgn  = (pos > 0.f) ? 1.f : ((pos < 0.f) ? -1.f : 0.f);

    double hl = exp2(3.0 + 8.0 * (double)f / 127.0);
    float e1 = (float)exp2(-(double)apos / hl);

    double cw = exp2((double)(f + 1)) - 1.0;
    float cm = (cw > (double)apos) ? 1.f : 0.f;

    double fp1 = (double)(f + 1);
    double conc = 4.0 * fp1 * fp1;
    double rate = 0.25 * fp1;
    double prob = 0.0;
    if (apos != 0.f) {
        double la = log((double)apos);
        double lu = (conc - 1.0) * la - rate * (double)apos;
        double ln = lgamma(conc) - conc * log(rate);
        prob = exp(lu - ln);
    }
    float pr = (float)prob;

    float* row = pe + (size_t)t * DM;
    row[f]        = e1;
    row[128 + f]  = e1 * sgn;
    row[256 + f]  = cm;
    row[384 + f]  = cm * sgn;
    row[512 + f]  = pr;
    row[640 + f]  = pr * sgn;

    __shared__ float red[128];
    red[f] = pr;
    __syncthreads();
    for (int s = 64; s > 0; s >>= 1) {
        if (f < s) red[f] = fmaxf(red[f], red[f + s]);
        __syncthreads();
    }
    if (f == 0) atomicMax((int*)gmax, __float_as_int(red[0]));
}

__global__ __launch_bounds__(256) void pe_scale(float* __restrict__ pe, const float* __restrict__ gmax)
{
    float inv = 1.0f / (*gmax);
    int t = blockIdx.x;
    int c = threadIdx.x;
    pe[(size_t)t * DM + 512 + c] *= inv;
}

// ---------------- fp32 GEMM: C = A[M,768] @ W[768,768] ----------------
// mode 0: head-scatter bf16: dst_u16[((n>>6)*M + m)*64 + (n&63)] = bf16(alpha*acc)
// mode 1: row-major f32 + bias
__global__ __launch_bounds__(256) void gemm64(const float* __restrict__ A, const float* __restrict__ W,
                                              void* __restrict__ Cv, int M, float alpha, int mode,
                                              const float* __restrict__ bias)
{
    const int K = DM, N = DM;
    __shared__ float As[64][17];
    __shared__ float Ws[16][68];
    int tid = threadIdx.x;
    int row0 = blockIdx.x * 64, col0 = blockIdx.y * 64;
    int ty = tid >> 4, tx = tid & 15;

    float acc[4][4];
    #pragma unroll
    for (int i = 0; i < 4; ++i)
        #pragma unroll
        for (int j = 0; j < 4; ++j) acc[i][j] = 0.f;

    for (int k0 = 0; k0 < K; k0 += 16) {
        {
            int r = tid >> 2;
            int kc = (tid & 3) * 4;
            int gr = row0 + r;
            float4 v = make_float4(0, 0, 0, 0);
            if (gr < M) v = *(const float4*)&A[(size_t)gr * K + k0 + kc];
            As[r][kc] = v.x; As[r][kc + 1] = v.y; As[r][kc + 2] = v.z; As[r][kc + 3] = v.w;
        }
        {
            int r = tid >> 4;
            int c = (tid & 15) * 4;
            float4 v = *(const float4*)&W[(size_t)(k0 + r) * N + col0 + c];
            Ws[r][c] = v.x; Ws[r][c + 1] = v.y; Ws[r][c + 2] = v.z; Ws[r][c + 3] = v.w;
        }
        __syncthreads();
        #pragma unroll
        for (int kk = 0; kk < 16; ++kk) {
            float a[4], b[4];
            #pragma unroll
            for (int i = 0; i < 4; ++i) a[i] = As[ty * 4 + i][kk];
            #pragma unroll
            for (int j = 0; j < 4; ++j) b[j] = Ws[kk][tx * 4 + j];
            #pragma unroll
            for (int i = 0; i < 4; ++i)
                #pragma unroll
                for (int j = 0; j < 4; ++j) acc[i][j] = fmaf(a[i], b[j], acc[i][j]);
        }
        __syncthreads();
    }

    #pragma unroll
    for (int i = 0; i < 4; ++i) {
        int m = row0 + ty * 4 + i;
        if (m >= M) continue;
        #pragma unroll
        for (int j = 0; j < 4; ++j) {
            int n = col0 + tx * 4 + j;
            float v = acc[i][j];
            if (mode == 0) {
                int hh = n >> 6, d = n & 63;
                ((u16*)Cv)[((size_t)hh * M + m) * 64 + d] = f2bf(v * alpha);
            } else {
                ((float*)Cv)[(size_t)m * N + n] = v + bias[n];
            }
        }
    }
}

// ---------------- MFMA fused attention ----------------
// block = (64 q-rows, head), 4 waves x 16 rows, 256 threads.
// Pass A: logits (content MFMA + banded-rel MFMA), online row max/sum (no stores).
// Pass B: recompute logits, write normalized attn (f32, once), PV via MFMA.
#define WAVE_LDS_FENCE() asm volatile("s_waitcnt lgkmcnt(0)" ::: "memory")

__global__ __launch_bounds__(256) void attn_fused(
    const u16* __restrict__ qh, const u16* __restrict__ kh, const u16* __restrict__ vh,
    const u16* __restrict__ rk, const float* __restrict__ rw, const float* __restrict__ rr,
    float* __restrict__ attn, float* __restrict__ oh)
{
    __shared__ u16 lds_kh[64 * 72];      // kh tile [j][d]; reused as vT [d][j] in pass B
    __shared__ u16 lds_rk[128 * 72];     // rk window [t'rel][d]
    __shared__ u16 lds_relP[4 * 16 * 80];// per-wave rel_raw band / P scratch

    const int tid = threadIdx.x;
    const int h  = blockIdx.y;
    const int i0 = blockIdx.x * 64;
    const int w   = tid >> 6;
    const int l   = tid & 63;
    const int l15 = l & 15;
    const int lg  = l >> 4;

    const u16* qh_h = qh + (size_t)h * S_LEN * DEPTH;
    const u16* kh_h = kh + (size_t)h * S_LEN * DEPTH;
    const u16* vh_h = vh + (size_t)h * S_LEN * DEPTH;
    const u16* rk_h = rk + (size_t)h * T_LEN * DEPTH;
    float* attn_h = attn + ((size_t)h * S_LEN + i0) * S_LEN;

    // ---- A-fragments (constant per wave across all j): qw = qh+r_w, qr = qh+r_r, bf16 ----
    s16x8 qwf[2], qrf[2];
    {
        int arow = i0 + w * 16 + l15;
        #pragma unroll
        for (int ks = 0; ks < 2; ++ks) {
            int bd = ks * 32 + lg * 8;
            s16x8 qv = *(const s16x8*)&qh_h[(size_t)arow * DEPTH + bd];
            #pragma unroll
            for (int e = 0; e < 8; ++e) {
                float f = bf2f((u16)qv[e]);
                qwf[ks][e] = (short)f2bf(f + rw[h * 64 + bd + e]);
                qrf[ks][e] = (short)f2bf(f + rr[h * 64 + bd + e]);
            }
        }
    }

    u16* relw = &lds_relP[w * 16 * 80];
    const int pb  = 48 - w * 16;          // wave band base inside rk window
    const int tb0 = 1984 - i0;            // Tlo = tb0 + jt ; t'rel = t - Tlo

    float run_max[4], run_sum[4];
    #pragma unroll
    for (int rg = 0; rg < 4; ++rg) { run_max[rg] = -3.0e38f; run_sum[rg] = 0.f; }

    // =================== PASS A ===================
    for (int jt = 0; jt < S_LEN; jt += 64) {
        __syncthreads();
        // stage kh tile [64][64] bf16
        #pragma unroll
        for (int it = 0; it < 4; ++it) {
            int idx = it * 256 + tid;
            int j = idx >> 4, d4 = (idx & 15) << 2;
            *(u16x4*)&lds_kh[j * 72 + d4] = *(const u16x4*)&kh_h[(size_t)(jt + j) * DEPTH + d4];
        }
        // stage rk window [128][64] bf16, t = Tlo + t'rel
        int Tlo = tb0 + jt;
        #pragma unroll
        for (int it = 0; it < 8; ++it) {
            int idx = it * 256 + tid;
            int tr = idx >> 4, d4 = (idx & 15) << 2;
            int t = Tlo + tr;
            u16x4 v = {0, 0, 0, 0};
            if (t >= 0 && t < T_LEN) v = *(const u16x4*)&rk_h[(size_t)t * DEPTH + d4];
            *(u16x4*)&lds_rk[tr * 72 + d4] = v;
        }
        __syncthreads();

        f32x4 accC[4], accR[5];
        #pragma unroll
        for (int cb = 0; cb < 4; ++cb) accC[cb] = (f32x4){0.f, 0.f, 0.f, 0.f};
        #pragma unroll
        for (int tb = 0; tb < 5; ++tb) accR[tb] = (f32x4){0.f, 0.f, 0.f, 0.f};

        #pragma unroll
        for (int ks = 0; ks < 2; ++ks) {
            int off = ks * 32 + lg * 8;
            #pragma unroll
            for (int cb = 0; cb < 4; ++cb) {
                s16x8 b = *(const s16x8*)&lds_kh[(cb * 16 + l15) * 72 + off];
                accC[cb] = __builtin_amdgcn_mfma_f32_16x16x32_bf16(qwf[ks], b, accC[cb], 0, 0, 0);
            }
            #pragma unroll
            for (int tb = 0; tb < 5; ++tb) {
                s16x8 b = *(const s16x8*)&lds_rk[(pb + tb * 16 + l15) * 72 + off];
                accR[tb] = __builtin_amdgcn_mfma_f32_16x16x32_bf16(qrf[ks], b, accR[tb], 0, 0, 0);
            }
        }
        // dump rel band, gather diagonal: rel[row][j_loc] = relw[row][15 + j_loc - row]
        #pragma unroll
        for (int tb = 0; tb < 5; ++tb)
            #pragma unroll
            for (int rg = 0; rg < 4; ++rg)
                relw[(lg * 4 + rg) * 80 + tb * 16 + l15] = f2bf(accR[tb][rg]);
        WAVE_LDS_FENCE();
        #pragma unroll
        for (int cb = 0; cb < 4; ++cb)
            #pragma unroll
            for (int rg = 0; rg < 4; ++rg) {
                int row = lg * 4 + rg;
                accC[cb][rg] += bf2f(relw[row * 80 + 15 + cb * 16 + l15 - row]);
            }
        // online row stats (rows lg*4+rg, cols reduced over 4 cb in-lane + 16 lanes)
        #pragma unroll
        for (int rg = 0; rg < 4; ++rg) {
            float m = fmaxf(fmaxf(accC[0][rg], accC[1][rg]), fmaxf(accC[2][rg], accC[3][rg]));
            m = fmaxf(m, __shfl_xor(m, 1));
            m = fmaxf(m, __shfl_xor(m, 2));
            m = fmaxf(m, __shfl_xor(m, 4));
            m = fmaxf(m, __shfl_xor(m, 8));
            float nm = fmaxf(run_max[rg], m);
            float s = __expf(accC[0][rg] - nm) + __expf(accC[1][rg] - nm)
                    + __expf(accC[2][rg] - nm) + __expf(accC[3][rg] - nm);
            s += __shfl_xor(s, 1);
            s += __shfl_xor(s, 2);
            s += __shfl_xor(s, 4);
            s += __shfl_xor(s, 8);
            run_sum[rg] = run_sum[rg] * __expf(run_max[rg] - nm) + s;
            run_max[rg] = nm;
        }
    }

    float inv_sum[4];
    #pragma unroll
    for (int rg = 0; rg < 4; ++rg) inv_sum[rg] = 1.0f / run_sum[rg];

    f32x4 accO[4];
    #pragma unroll
    for (int db = 0; db < 4; ++db) accO[db] = (f32x4){0.f, 0.f, 0.f, 0.f};

    // =================== PASS B ===================
    for (int jt = 0; jt < S_LEN; jt += 64) {
        __syncthreads();
        #pragma unroll
        for (int it = 0; it < 4; ++it) {
            int idx = it * 256 + tid;
            int j = idx >> 4, d4 = (idx & 15) << 2;
            *(u16x4*)&lds_kh[j * 72 + d4] = *(const u16x4*)&kh_h[(size_t)(jt + j) * DEPTH + d4];
        }
        int Tlo = tb0 + jt;
        #pragma unroll
        for (int it = 0; it < 8; ++it) {
            int idx = it * 256 + tid;
            int tr = idx >> 4, d4 = (idx & 15) << 2;
            int t = Tlo + tr;
            u16x4 v = {0, 0, 0, 0};
            if (t >= 0 && t < T_LEN) v = *(const u16x4*)&rk_h[(size_t)t * DEPTH + d4];
            *(u16x4*)&lds_rk[tr * 72 + d4] = v;
        }
        __syncthreads();

        f32x4 accC[4], accR[5];
        #pragma unroll
        for (int cb = 0; cb < 4; ++cb) accC[cb] = (f32x4){0.f, 0.f, 0.f, 0.f};
        #pragma unroll
        for (int tb = 0; tb < 5; ++tb) accR[tb] = (f32x4){0.f, 0.f, 0.f, 0.f};

        #pragma unroll
        for (int ks = 0; ks < 2; ++ks) {
            int off = ks * 32 + lg * 8;
            #pragma unroll
            for (int cb = 0; cb < 4; ++cb) {
                s16x8 b = *(const s16x8*)&lds_kh[(cb * 16 + l15) * 72 + off];
                accC[cb] = __builtin_amdgcn_mfma_f32_16x16x32_bf16(qwf[ks], b, accC[cb], 0, 0, 0);
            }
            #pragma unroll
            for (int tb = 0; tb < 5; ++tb) {
                s16x8 b = *(const s16x8*)&lds_rk[(pb + tb * 16 + l15) * 72 + off];
                accR[tb] = __builtin_amdgcn_mfma_f32_16x16x32_bf16(qrf[ks], b, accR[tb], 0, 0, 0);
            }
        }
        #pragma unroll
        for (int tb = 0; tb < 5; ++tb)
            #pragma unroll
            for (int rg = 0; rg < 4; ++rg)
                relw[(lg * 4 + rg) * 80 + tb * 16 + l15] = f2bf(accR[tb][rg]);
        WAVE_LDS_FENCE();
        // P = softmax value; write attn (f32) + P (bf16) into wave scratch
        #pragma unroll
        for (int cb = 0; cb < 4; ++cb)
            #pragma unroll
            for (int rg = 0; rg < 4; ++rg) {
                int row = lg * 4 + rg;
                float lgt = accC[cb][rg] + bf2f(relw[row * 80 + 15 + cb * 16 + l15 - row]);
                float pr = __expf(lgt - run_max[rg]) * inv_sum[rg];
                attn_h[(size_t)(w * 16 + row) * S_LEN + jt + cb * 16 + l15] = pr;
                relw[row * 80 + cb * 16 + l15] = f2bf(pr);   // band area dead; reuse as P
            }
        __syncthreads();   // all waves done reading lds_kh (kh tile)
        // stage V transposed: vT[d][j] over lds_kh
        #pragma unroll
        for (int it = 0; it < 4; ++it) {
            int idx = it * 256 + tid;
            int j = idx & 63, d4 = (idx >> 6) << 2;
            u16x4 v = *(const u16x4*)&vh_h[(size_t)(jt + j) * DEPTH + d4];
            lds_kh[(d4 + 0) * 72 + j] = v.x;
            lds_kh[(d4 + 1) * 72 + j] = v.y;
            lds_kh[(d4 + 2) * 72 + j] = v.z;
            lds_kh[(d4 + 3) * 72 + j] = v.w;
        }
        __syncthreads();
        // PV: out[16 i][64 d] += P[16 i][64 j] * V[64 j][64 d]
        s16x8 pA[2];
        #pragma unroll
        for (int ks = 0; ks < 2; ++ks)
            pA[ks] = *(const s16x8*)&relw[l15 * 80 + ks * 32 + lg * 8];
        #pragma unroll
        for (int ks = 0; ks < 2; ++ks) {
            int off = ks * 32 + lg * 8;
            #pragma unroll
            for (int db = 0; db < 4; ++db) {
                s16x8 bv = *(const s16x8*)&lds_kh[(db * 16 + l15) * 72 + off];
                accO[db] = __builtin_amdgcn_mfma_f32_16x16x32_bf16(pA[ks], bv, accO[db], 0, 0, 0);
            }
        }
    }

    // write oh (merged-head f32) for the out-projection GEMM
    #pragma unroll
    for (int db = 0; db < 4; ++db)
        #pragma unroll
        for (int rg = 0; rg < 4; ++rg)
            oh[(size_t)(i0 + w * 16 + lg * 4 + rg) * DM + h * 64 + db * 16 + l15] = accO[db][rg];
}

extern "C" void kernel_launch(void* const* d_in, const int* in_sizes, int n_in,
                              void* d_out, int out_size, void* d_ws, size_t ws_size,
                              hipStream_t stream) {
    const float* q    = (const float*)d_in[0];
    const float* k    = (const float*)d_in[1];
    const float* v    = (const float*)d_in[2];
    const float* wq   = (const float*)d_in[3];
    const float* wk   = (const float*)d_in[4];
    const float* wv   = (const float*)d_in[5];
    const float* w_rk = (const float*)d_in[6];
    const float* r_w  = (const float*)d_in[7];
    const float* r_r  = (const float*)d_in[8];
    const float* w_out= (const float*)d_in[9];
    const float* b_out= (const float*)d_in[10];

    float* outp = (float*)d_out;                       // [2048][768]
    float* attn = outp + (size_t)S_LEN * DM;           // [12][2048][2048]

    if (ws_size < WS_NEEDED_BYTES) {
        hipLaunchKernelGGL(ws_too_small, dim3(1), dim3(1), 0, stream, outp, (float)ws_size);
        return;
    }

    float* ws = (float*)d_ws;
    u16* qh = (u16*)(ws + QH_OFF);
    u16* kh = (u16*)(ws + KH_OFF);
    u16* vh = (u16*)(ws + VH_OFF);
    u16* rk = (u16*)(ws + RK_OFF);
    float* oh = ws + OH_OFF;
    float* gmax = ws + GMAX_OFF;
    float* pe = attn;                                  // [4095][768] f32 — dead before attn written

    hipLaunchKernelGGL(init_gmax, dim3(1), dim3(1), 0, stream, gmax);

    // projections (head-scatter, bf16 out). qh scaled by 1/sqrt(64)
    hipLaunchKernelGGL(gemm64, dim3(32, 12), dim3(256), 0, stream, q, wq, (void*)qh, S_LEN, 0.125f, 0, (const float*)nullptr);
    hipLaunchKernelGGL(gemm64, dim3(32, 12), dim3(256), 0, stream, k, wk, (void*)kh, S_LEN, 1.0f, 0, (const float*)nullptr);
    hipLaunchKernelGGL(gemm64, dim3(32, 12), dim3(256), 0, stream, v, wv, (void*)vh, S_LEN, 1.0f, 0, (const float*)nullptr);

    // positional features
    hipLaunchKernelGGL(pe_kernel, dim3(T_LEN), dim3(128), 0, stream, pe, gmax);
    hipLaunchKernelGGL(pe_scale, dim3(T_LEN), dim3(256), 0, stream, pe, gmax);

    // rk = pe @ w_rk (head-scatter bf16, M=4095)
    hipLaunchKernelGGL(gemm64, dim3(64, 12), dim3(256), 0, stream, pe, w_rk, (void*)rk, T_LEN, 1.0f, 0, (const float*)nullptr);

    // fused MFMA attention
    hipLaunchKernelGGL(attn_fused, dim3(S_LEN / 64, NH), dim3(256), 0, stream,
                       qh, kh, vh, rk, r_w, r_r, attn, oh);

    // output projection + bias (f32)
    hipLaunchKernelGGL(gemm64, dim3(32, 12), dim3(256), 0, stream, oh, w_out, (void*)outp, S_LEN, 1.0f, 1, b_out);
}

// Round 5
// 681.873 us; speedup vs baseline: 1.9261x; 1.2894x over previous
//
#include <hip/hip_runtime.h>
#include <math.h>

#define S_LEN 2048
#define T_LEN 4095
#define NH 12
#define DEPTH 64
#define DM 768

typedef unsigned short u16;
typedef u16   u16x4 __attribute__((ext_vector_type(4)));
typedef short s16x8 __attribute__((ext_vector_type(8)));   // 8 bf16 (4 VGPRs) MFMA frag
typedef float f32x4 __attribute__((ext_vector_type(4)));   // MFMA accumulator

// ---- workspace layout (u16 units) ----
#define QH_OFF  ((size_t)0)
#define KH_OFF  (QH_OFF + (size_t)NH*S_LEN*DEPTH)
#define VH_OFF  (KH_OFF + (size_t)NH*S_LEN*DEPTH)
#define RK_OFF  (VH_OFF + (size_t)NH*S_LEN*DEPTH)
#define OH_OFF  (RK_OFF + (size_t)NH*T_LEN*DEPTH)
#define WTO_OFF (OH_OFF + (size_t)S_LEN*DM)
#define GMAX_OFF (WTO_OFF + (size_t)DM*DM)
#define WS_NEEDED_BYTES ((GMAX_OFF + 32) * sizeof(u16))

// scratch inside d_out's attn region (u16 offsets from attn base; dead before attn_fused)
#define PEB_OFF ((size_t)0)                          // [4095][768] bf16
#define QB_OFF  (PEB_OFF + (size_t)T_LEN*DM)
#define KB_OFF  (QB_OFF + (size_t)S_LEN*DM)
#define VB_OFF  (KB_OFF + (size_t)S_LEN*DM)
#define WTQ_OFF (VB_OFF + (size_t)S_LEN*DM)
#define WTK_OFF (WTQ_OFF + (size_t)DM*DM)
#define WTV_OFF (WTK_OFF + (size_t)DM*DM)
#define WTR_OFF (WTV_OFF + (size_t)DM*DM)

__device__ __forceinline__ float bf2f(u16 x) {
    union { unsigned u; float f; } c; c.u = ((unsigned)x) << 16; return c.f;
}
__device__ __forceinline__ u16 f2bf(float f) {
    union { float f; unsigned u; } c; c.f = f;
    unsigned u = c.u;
    return (u16)((u + 0x7FFFu + ((u >> 16) & 1u)) >> 16);
}

__global__ void init_gmax(float* g) { *g = 0.0f; }
__global__ void ws_too_small(float* out, float wsz) { out[0] = wsz; }

// ---------------- f32 -> bf16 convert ----------------
__global__ __launch_bounds__(256) void cvt_bf16(const float* __restrict__ in, u16* __restrict__ out, int n4)
{
    int i = blockIdx.x * 256 + threadIdx.x;
    if (i < n4) {
        float4 v = ((const float4*)in)[i];
        u16x4 o = { f2bf(v.x), f2bf(v.y), f2bf(v.z), f2bf(v.w) };
        ((u16x4*)out)[i] = o;
    }
}

// ---------------- weight transpose + bf16 (+ optional row-scale by 1/gmax for k>=scale_from) ----
__global__ __launch_bounds__(256) void wtrans(const float* __restrict__ W, u16* __restrict__ WT,
                                              const float* __restrict__ gmax, int scale_from)
{
    __shared__ float t[64][65];
    int k0 = blockIdx.x * 64, n0 = blockIdx.y * 64;
    int tid = threadIdx.x;
    float inv = (scale_from < DM) ? (1.0f / (*gmax)) : 1.0f;

    #pragma unroll
    for (int it = 0; it < 4; ++it) {
        int idx = it * 256 + tid;
        int r = idx >> 4, c4 = (idx & 15) << 2;
        float4 v = *(const float4*)&W[(size_t)(k0 + r) * DM + n0 + c4];
        t[r][c4] = v.x; t[r][c4 + 1] = v.y; t[r][c4 + 2] = v.z; t[r][c4 + 3] = v.w;
    }
    __syncthreads();
    #pragma unroll
    for (int it = 0; it < 4; ++it) {
        int idx = it * 256 + tid;
        int rn = idx >> 4, k4 = (idx & 15) << 2;
        u16x4 o;
        #pragma unroll
        for (int e = 0; e < 4; ++e) {
            float f = t[k4 + e][rn];
            if (k0 + k4 + e >= scale_from) f *= inv;
            o[e] = f2bf(f);
        }
        *(u16x4*)&WT[(size_t)(n0 + rn) * DM + k0 + k4] = o;
    }
}

// ---------------- positional features (bf16 out) ----------------
__global__ __launch_bounds__(128) void pe_kernel(u16* __restrict__ pe, float* __restrict__ gmax)
{
    int t = blockIdx.x;
    int f = threadIdx.x;
    float pos  = (float)(t - (S_LEN - 1));
    float apos = fabsf(pos);
    float sgn  = (pos > 0.f) ? 1.f : ((pos < 0.f) ? -1.f : 0.f);

    double hl = exp2(3.0 + 8.0 * (double)f / 127.0);
    float e1 = (float)exp2(-(double)apos / hl);

    double cw = exp2((double)(f + 1)) - 1.0;
    float cm = (cw > (double)apos) ? 1.f : 0.f;

    double fp1 = (double)(f + 1);
    double conc = 4.0 * fp1 * fp1;
    double rate = 0.25 * fp1;
    double prob = 0.0;
    if (apos != 0.f) {
        double la = log((double)apos);
        double lu = (conc - 1.0) * la - rate * (double)apos;
        double ln = lgamma(conc) - conc * log(rate);
        prob = exp(lu - ln);
    }
    float pr = (float)prob;

    u16* row = pe + (size_t)t * DM;
    row[f]        = f2bf(e1);
    row[128 + f]  = f2bf(e1 * sgn);
    row[256 + f]  = f2bf(cm);
    row[384 + f]  = f2bf(cm * sgn);
    row[512 + f]  = f2bf(pr);        // unnormalized; 1/gmax folded into wT(w_rk)
    row[640 + f]  = f2bf(pr * sgn);

    __shared__ float red[128];
    red[f] = pr;
    __syncthreads();
    for (int s = 64; s > 0; s >>= 1) {
        if (f < s) red[f] = fmaxf(red[f], red[f + s]);
        __syncthreads();
    }
    if (f == 0) atomicMax((int*)gmax, __float_as_int(red[0]));
}

// ---------------- bf16 MFMA GEMM: C = A[M,768] @ WT[768,768]^T ----------------
// A bf16 [m][k]; WT bf16 [n][k]. 64x64 tile, 4 waves (16 rows each), 256 threads.
// mode 0: head-scatter bf16: dst[((by*M + m)*64 + (n&63)] = bf16(alpha*acc)
// mode 1: f32 row-major + bias
__global__ __launch_bounds__(256) void gemm_bf(const u16* __restrict__ A, const u16* __restrict__ WT,
                                               void* __restrict__ Cv, int M, float alpha, int mode,
                                               const float* __restrict__ bias)
{
    __shared__ u16 As[64 * 72];
    __shared__ u16 Ws[64 * 72];
    int tid = threadIdx.x;
    int row0 = blockIdx.x * 64, col0 = blockIdx.y * 64;
    int w = tid >> 6, l = tid & 63, l15 = l & 15, lg = l >> 4;

    f32x4 acc[4];
    #pragma unroll
    for (int cb = 0; cb < 4; ++cb) acc[cb] = (f32x4){0.f, 0.f, 0.f, 0.f};

    for (int k0 = 0; k0 < DM; k0 += 64) {
        __syncthreads();
        #pragma unroll
        for (int it = 0; it < 4; ++it) {
            int idx = it * 256 + tid;
            int r = idx >> 4, c4 = (idx & 15) << 2;
            int gr = row0 + r;
            u16x4 va = {0, 0, 0, 0};
            if (gr < M) va = *(const u16x4*)&A[(size_t)gr * DM + k0 + c4];
            *(u16x4*)&As[r * 72 + c4] = va;
            *(u16x4*)&Ws[r * 72 + c4] = *(const u16x4*)&WT[(size_t)(col0 + r) * DM + k0 + c4];
        }
        __syncthreads();
        #pragma unroll
        for (int ks = 0; ks < 2; ++ks) {
            int off = ks * 32 + lg * 8;
            s16x8 aF = *(const s16x8*)&As[(w * 16 + l15) * 72 + off];
            #pragma unroll
            for (int cb = 0; cb < 4; ++cb) {
                s16x8 bF = *(const s16x8*)&Ws[(cb * 16 + l15) * 72 + off];
                acc[cb] = __builtin_amdgcn_mfma_f32_16x16x32_bf16(aF, bF, acc[cb], 0, 0, 0);
            }
        }
    }

    #pragma unroll
    for (int cb = 0; cb < 4; ++cb)
        #pragma unroll
        for (int rg = 0; rg < 4; ++rg) {
            int m = row0 + w * 16 + lg * 4 + rg;
            if (m >= M) continue;
            int nl = cb * 16 + l15;
            if (mode == 0) {
                ((u16*)Cv)[((size_t)blockIdx.y * M + m) * 64 + nl] = f2bf(acc[cb][rg] * alpha);
            } else {
                ((float*)Cv)[(size_t)m * DM + col0 + nl] = acc[cb][rg] + bias[col0 + nl];
            }
        }
}

// ---------------- MFMA fused attention ----------------
#define WAVE_LDS_FENCE() asm volatile("s_waitcnt lgkmcnt(0)" ::: "memory")

__global__ __launch_bounds__(256) void attn_fused(
    const u16* __restrict__ qh, const u16* __restrict__ kh, const u16* __restrict__ vh,
    const u16* __restrict__ rk, const float* __restrict__ rw, const float* __restrict__ rr,
    float* __restrict__ attn, u16* __restrict__ oh)
{
    __shared__ u16 lds_kh[64 * 72];      // kh tile [j][d]; reused as vT [d][j] in pass B
    __shared__ u16 lds_rk[128 * 72];     // rk window [t'rel][d]
    __shared__ u16 lds_relP[4 * 16 * 80];// per-wave rel_raw band / P scratch

    const int tid = threadIdx.x;
    const int h  = blockIdx.y;
    const int i0 = blockIdx.x * 64;
    const int w   = tid >> 6;
    const int l   = tid & 63;
    const int l15 = l & 15;
    const int lg  = l >> 4;

    const u16* qh_h = qh + (size_t)h * S_LEN * DEPTH;
    const u16* kh_h = kh + (size_t)h * S_LEN * DEPTH;
    const u16* vh_h = vh + (size_t)h * S_LEN * DEPTH;
    const u16* rk_h = rk + (size_t)h * T_LEN * DEPTH;
    float* attn_h = attn + ((size_t)h * S_LEN + i0) * S_LEN;

    s16x8 qwf[2], qrf[2];
    {
        int arow = i0 + w * 16 + l15;
        #pragma unroll
        for (int ks = 0; ks < 2; ++ks) {
            int bd = ks * 32 + lg * 8;
            s16x8 qv = *(const s16x8*)&qh_h[(size_t)arow * DEPTH + bd];
            #pragma unroll
            for (int e = 0; e < 8; ++e) {
                float f = bf2f((u16)qv[e]);
                qwf[ks][e] = (short)f2bf(f + rw[h * 64 + bd + e]);
                qrf[ks][e] = (short)f2bf(f + rr[h * 64 + bd + e]);
            }
        }
    }

    u16* relw = &lds_relP[w * 16 * 80];
    const int pb  = 48 - w * 16;
    const int tb0 = 1984 - i0;

    float run_max[4], run_sum[4];
    #pragma unroll
    for (int rg = 0; rg < 4; ++rg) { run_max[rg] = -3.0e38f; run_sum[rg] = 0.f; }

    // =================== PASS A ===================
    for (int jt = 0; jt < S_LEN; jt += 64) {
        __syncthreads();
        #pragma unroll
        for (int it = 0; it < 4; ++it) {
            int idx = it * 256 + tid;
            int j = idx >> 4, d4 = (idx & 15) << 2;
            *(u16x4*)&lds_kh[j * 72 + d4] = *(const u16x4*)&kh_h[(size_t)(jt + j) * DEPTH + d4];
        }
        int Tlo = tb0 + jt;
        #pragma unroll
        for (int it = 0; it < 8; ++it) {
            int idx = it * 256 + tid;
            int tr = idx >> 4, d4 = (idx & 15) << 2;
            int t = Tlo + tr;
            u16x4 v = {0, 0, 0, 0};
            if (t >= 0 && t < T_LEN) v = *(const u16x4*)&rk_h[(size_t)t * DEPTH + d4];
            *(u16x4*)&lds_rk[tr * 72 + d4] = v;
        }
        __syncthreads();

        f32x4 accC[4], accR[5];
        #pragma unroll
        for (int cb = 0; cb < 4; ++cb) accC[cb] = (f32x4){0.f, 0.f, 0.f, 0.f};
        #pragma unroll
        for (int tb = 0; tb < 5; ++tb) accR[tb] = (f32x4){0.f, 0.f, 0.f, 0.f};

        #pragma unroll
        for (int ks = 0; ks < 2; ++ks) {
            int off = ks * 32 + lg * 8;
            #pragma unroll
            for (int cb = 0; cb < 4; ++cb) {
                s16x8 b = *(const s16x8*)&lds_kh[(cb * 16 + l15) * 72 + off];
                accC[cb] = __builtin_amdgcn_mfma_f32_16x16x32_bf16(qwf[ks], b, accC[cb], 0, 0, 0);
            }
            #pragma unroll
            for (int tb = 0; tb < 5; ++tb) {
                s16x8 b = *(const s16x8*)&lds_rk[(pb + tb * 16 + l15) * 72 + off];
                accR[tb] = __builtin_amdgcn_mfma_f32_16x16x32_bf16(qrf[ks], b, accR[tb], 0, 0, 0);
            }
        }
        #pragma unroll
        for (int tb = 0; tb < 5; ++tb)
            #pragma unroll
            for (int rg = 0; rg < 4; ++rg)
                relw[(lg * 4 + rg) * 80 + tb * 16 + l15] = f2bf(accR[tb][rg]);
        WAVE_LDS_FENCE();
        #pragma unroll
        for (int cb = 0; cb < 4; ++cb)
            #pragma unroll
            for (int rg = 0; rg < 4; ++rg) {
                int row = lg * 4 + rg;
                accC[cb][rg] += bf2f(relw[row * 80 + 15 + cb * 16 + l15 - row]);
            }
        #pragma unroll
        for (int rg = 0; rg < 4; ++rg) {
            float m = fmaxf(fmaxf(accC[0][rg], accC[1][rg]), fmaxf(accC[2][rg], accC[3][rg]));
            m = fmaxf(m, __shfl_xor(m, 1));
            m = fmaxf(m, __shfl_xor(m, 2));
            m = fmaxf(m, __shfl_xor(m, 4));
            m = fmaxf(m, __shfl_xor(m, 8));
            float nm = fmaxf(run_max[rg], m);
            float s = __expf(accC[0][rg] - nm) + __expf(accC[1][rg] - nm)
                    + __expf(accC[2][rg] - nm) + __expf(accC[3][rg] - nm);
            s += __shfl_xor(s, 1);
            s += __shfl_xor(s, 2);
            s += __shfl_xor(s, 4);
            s += __shfl_xor(s, 8);
            run_sum[rg] = run_sum[rg] * __expf(run_max[rg] - nm) + s;
            run_max[rg] = nm;
        }
    }

    float inv_sum[4];
    #pragma unroll
    for (int rg = 0; rg < 4; ++rg) inv_sum[rg] = 1.0f / run_sum[rg];

    f32x4 accO[4];
    #pragma unroll
    for (int db = 0; db < 4; ++db) accO[db] = (f32x4){0.f, 0.f, 0.f, 0.f};

    // =================== PASS B ===================
    for (int jt = 0; jt < S_LEN; jt += 64) {
        __syncthreads();
        #pragma unroll
        for (int it = 0; it < 4; ++it) {
            int idx = it * 256 + tid;
            int j = idx >> 4, d4 = (idx & 15) << 2;
            *(u16x4*)&lds_kh[j * 72 + d4] = *(const u16x4*)&kh_h[(size_t)(jt + j) * DEPTH + d4];
        }
        int Tlo = tb0 + jt;
        #pragma unroll
        for (int it = 0; it < 8; ++it) {
            int idx = it * 256 + tid;
            int tr = idx >> 4, d4 = (idx & 15) << 2;
            int t = Tlo + tr;
            u16x4 v = {0, 0, 0, 0};
            if (t >= 0 && t < T_LEN) v = *(const u16x4*)&rk_h[(size_t)t * DEPTH + d4];
            *(u16x4*)&lds_rk[tr * 72 + d4] = v;
        }
        __syncthreads();

        f32x4 accC[4], accR[5];
        #pragma unroll
        for (int cb = 0; cb < 4; ++cb) accC[cb] = (f32x4){0.f, 0.f, 0.f, 0.f};
        #pragma unroll
        for (int tb = 0; tb < 5; ++tb) accR[tb] = (f32x4){0.f, 0.f, 0.f, 0.f};

        #pragma unroll
        for (int ks = 0; ks < 2; ++ks) {
            int off = ks * 32 + lg * 8;
            #pragma unroll
            for (int cb = 0; cb < 4; ++cb) {
                s16x8 b = *(const s16x8*)&lds_kh[(cb * 16 + l15) * 72 + off];
                accC[cb] = __builtin_amdgcn_mfma_f32_16x16x32_bf16(qwf[ks], b, accC[cb], 0, 0, 0);
            }
            #pragma unroll
            for (int tb = 0; tb < 5; ++tb) {
                s16x8 b = *(const s16x8*)&lds_rk[(pb + tb * 16 + l15) * 72 + off];
                accR[tb] = __builtin_amdgcn_mfma_f32_16x16x32_bf16(qrf[ks], b, accR[tb], 0, 0, 0);
            }
        }
        #pragma unroll
        for (int tb = 0; tb < 5; ++tb)
            #pragma unroll
            for (int rg = 0; rg < 4; ++rg)
                relw[(lg * 4 + rg) * 80 + tb * 16 + l15] = f2bf(accR[tb][rg]);
        WAVE_LDS_FENCE();
        #pragma unroll
        for (int cb = 0; cb < 4; ++cb)
            #pragma unroll
            for (int rg = 0; rg < 4; ++rg) {
                int row = lg * 4 + rg;
                float lgt = accC[cb][rg] + bf2f(relw[row * 80 + 15 + cb * 16 + l15 - row]);
                float pr = __expf(lgt - run_max[rg]) * inv_sum[rg];
                attn_h[(size_t)(w * 16 + row) * S_LEN + jt + cb * 16 + l15] = pr;
                relw[row * 80 + cb * 16 + l15] = f2bf(pr);
            }
        __syncthreads();
        #pragma unroll
        for (int it = 0; it < 4; ++it) {
            int idx = it * 256 + tid;
            int j = idx & 63, d4 = (idx >> 6) << 2;
            u16x4 v = *(const u16x4*)&vh_h[(size_t)(jt + j) * DEPTH + d4];
            lds_kh[(d4 + 0) * 72 + j] = v.x;
            lds_kh[(d4 + 1) * 72 + j] = v.y;
            lds_kh[(d4 + 2) * 72 + j] = v.z;
            lds_kh[(d4 + 3) * 72 + j] = v.w;
        }
        __syncthreads();
        s16x8 pA[2];
        #pragma unroll
        for (int ks = 0; ks < 2; ++ks)
            pA[ks] = *(const s16x8*)&relw[l15 * 80 + ks * 32 + lg * 8];
        #pragma unroll
        for (int ks = 0; ks < 2; ++ks) {
            int off = ks * 32 + lg * 8;
            #pragma unroll
            for (int db = 0; db < 4; ++db) {
                s16x8 bv = *(const s16x8*)&lds_kh[(db * 16 + l15) * 72 + off];
                accO[db] = __builtin_amdgcn_mfma_f32_16x16x32_bf16(pA[ks], bv, accO[db], 0, 0, 0);
            }
        }
    }

    #pragma unroll
    for (int db = 0; db < 4; ++db)
        #pragma unroll
        for (int rg = 0; rg < 4; ++rg)
            oh[(size_t)(i0 + w * 16 + lg * 4 + rg) * DM + h * 64 + db * 16 + l15] = f2bf(accO[db][rg]);
}

extern "C" void kernel_launch(void* const* d_in, const int* in_sizes, int n_in,
                              void* d_out, int out_size, void* d_ws, size_t ws_size,
                              hipStream_t stream) {
    const float* q    = (const float*)d_in[0];
    const float* k    = (const float*)d_in[1];
    const float* v    = (const float*)d_in[2];
    const float* wq   = (const float*)d_in[3];
    const float* wk   = (const float*)d_in[4];
    const float* wv   = (const float*)d_in[5];
    const float* w_rk = (const float*)d_in[6];
    const float* r_w  = (const float*)d_in[7];
    const float* r_r  = (const float*)d_in[8];
    const float* w_out= (const float*)d_in[9];
    const float* b_out= (const float*)d_in[10];

    float* outp = (float*)d_out;                       // [2048][768]
    float* attn = outp + (size_t)S_LEN * DM;           // [12][2048][2048]

    if (ws_size < WS_NEEDED_BYTES) {
        hipLaunchKernelGGL(ws_too_small, dim3(1), dim3(1), 0, stream, outp, (float)ws_size);
        return;
    }

    u16* wsb = (u16*)d_ws;
    u16* qh = wsb + QH_OFF;
    u16* kh = wsb + KH_OFF;
    u16* vh = wsb + VH_OFF;
    u16* rk = wsb + RK_OFF;
    u16* oh = wsb + OH_OFF;
    u16* wTo = wsb + WTO_OFF;
    float* gmax = (float*)(wsb + GMAX_OFF);

    u16* scratch = (u16*)attn;                         // dead until attn_fused
    u16* peb = scratch + PEB_OFF;
    u16* qb  = scratch + QB_OFF;
    u16* kb  = scratch + KB_OFF;
    u16* vb  = scratch + VB_OFF;
    u16* wTq = scratch + WTQ_OFF;
    u16* wTk = scratch + WTK_OFF;
    u16* wTv = scratch + WTV_OFF;
    u16* wTr = scratch + WTR_OFF;

    const int n4 = S_LEN * DM / 4;
    hipLaunchKernelGGL(cvt_bf16, dim3((n4 + 255) / 256), dim3(256), 0, stream, q, qb, n4);
    hipLaunchKernelGGL(cvt_bf16, dim3((n4 + 255) / 256), dim3(256), 0, stream, k, kb, n4);
    hipLaunchKernelGGL(cvt_bf16, dim3((n4 + 255) / 256), dim3(256), 0, stream, v, vb, n4);

    hipLaunchKernelGGL(init_gmax, dim3(1), dim3(1), 0, stream, gmax);
    hipLaunchKernelGGL(pe_kernel, dim3(T_LEN), dim3(128), 0, stream, peb, gmax);

    hipLaunchKernelGGL(wtrans, dim3(12, 12), dim3(256), 0, stream, wq, wTq, gmax, 1 << 30);
    hipLaunchKernelGGL(wtrans, dim3(12, 12), dim3(256), 0, stream, wk, wTk, gmax, 1 << 30);
    hipLaunchKernelGGL(wtrans, dim3(12, 12), dim3(256), 0, stream, wv, wTv, gmax, 1 << 30);
    hipLaunchKernelGGL(wtrans, dim3(12, 12), dim3(256), 0, stream, w_rk, wTr, gmax, 512);
    hipLaunchKernelGGL(wtrans, dim3(12, 12), dim3(256), 0, stream, w_out, wTo, gmax, 1 << 30);

    // projections (head-scatter bf16). qh scaled by 1/sqrt(64)
    hipLaunchKernelGGL(gemm_bf, dim3(32, 12), dim3(256), 0, stream, qb, wTq, (void*)qh, S_LEN, 0.125f, 0, (const float*)nullptr);
    hipLaunchKernelGGL(gemm_bf, dim3(32, 12), dim3(256), 0, stream, kb, wTk, (void*)kh, S_LEN, 1.0f, 0, (const float*)nullptr);
    hipLaunchKernelGGL(gemm_bf, dim3(32, 12), dim3(256), 0, stream, vb, wTv, (void*)vh, S_LEN, 1.0f, 0, (const float*)nullptr);

    // rk = pe @ w_rk (head-scatter bf16, M=4095)
    hipLaunchKernelGGL(gemm_bf, dim3(64, 12), dim3(256), 0, stream, peb, wTr, (void*)rk, T_LEN, 1.0f, 0, (const float*)nullptr);

    // fused MFMA attention (overwrites scratch region with attn probs)
    hipLaunchKernelGGL(attn_fused, dim3(S_LEN / 64, NH), dim3(256), 0, stream,
                       qh, kh, vh, rk, r_w, r_r, attn, oh);

    // output projection + bias (f32)
    hipLaunchKernelGGL(gemm_bf, dim3(32, 12), dim3(256), 0, stream, oh, wTo, (void*)outp, S_LEN, 1.0f, 1, b_out);
}

// Round 6
// 675.149 us; speedup vs baseline: 1.9453x; 1.0100x over previous
//
#include <hip/hip_runtime.h>
#include <math.h>

#define S_LEN 2048
#define T_LEN 4095
#define NH 12
#define DEPTH 64
#define DM 768

typedef unsigned short u16;
typedef u16   u16x4 __attribute__((ext_vector_type(4)));
typedef short s16x8 __attribute__((ext_vector_type(8)));   // 8 bf16 (4 VGPRs) MFMA frag
typedef float f32x4 __attribute__((ext_vector_type(4)));   // MFMA accumulator

// ---- workspace layout (u16 units) ----
#define QH_OFF  ((size_t)0)
#define KH_OFF  (QH_OFF + (size_t)NH*S_LEN*DEPTH)
#define VH_OFF  (KH_OFF + (size_t)NH*S_LEN*DEPTH)
#define RK_OFF  (VH_OFF + (size_t)NH*S_LEN*DEPTH)
#define OH_OFF  (RK_OFF + (size_t)NH*T_LEN*DEPTH)
#define WTO_OFF (OH_OFF + (size_t)S_LEN*DM)
#define GMAX_OFF (WTO_OFF + (size_t)DM*DM)
#define WS_NEEDED_BYTES ((GMAX_OFF + 32) * sizeof(u16))

// scratch inside d_out's attn region (u16 offsets; dead before attn_fused writes attn)
#define PEB_OFF ((size_t)0)                          // [4095][768] bf16
#define WTQ_OFF (PEB_OFF + (size_t)T_LEN*DM)
#define WTK_OFF (WTQ_OFF + (size_t)DM*DM)
#define WTV_OFF (WTK_OFF + (size_t)DM*DM)
#define WTR_OFF (WTV_OFF + (size_t)DM*DM)

__device__ __forceinline__ float bf2f(u16 x) {
    union { unsigned u; float f; } c; c.u = ((unsigned)x) << 16; return c.f;
}
__device__ __forceinline__ u16 f2bf(float f) {
    union { float f; unsigned u; } c; c.f = f;
    unsigned u = c.u;
    return (u16)((u + 0x7FFFu + ((u >> 16) & 1u)) >> 16);
}

__global__ void init_gmax(float* g) { *g = 0.0f; }
__global__ void ws_too_small(float* out, float wsz) { out[0] = wsz; }

// ---------------- positional features (bf16 out) ----------------
__global__ __launch_bounds__(128) void pe_kernel(u16* __restrict__ pe, float* __restrict__ gmax)
{
    int t = blockIdx.x;
    int f = threadIdx.x;
    float pos  = (float)(t - (S_LEN - 1));
    float apos = fabsf(pos);
    float sgn  = (pos > 0.f) ? 1.f : ((pos < 0.f) ? -1.f : 0.f);

    double hl = exp2(3.0 + 8.0 * (double)f / 127.0);
    float e1 = (float)exp2(-(double)apos / hl);

    double cw = exp2((double)(f + 1)) - 1.0;
    float cm = (cw > (double)apos) ? 1.f : 0.f;

    double fp1 = (double)(f + 1);
    double conc = 4.0 * fp1 * fp1;
    double rate = 0.25 * fp1;
    double prob = 0.0;
    if (apos != 0.f) {
        double la = log((double)apos);
        double lu = (conc - 1.0) * la - rate * (double)apos;
        double ln = lgamma(conc) - conc * log(rate);
        prob = exp(lu - ln);
    }
    float pr = (float)prob;

    u16* row = pe + (size_t)t * DM;
    row[f]        = f2bf(e1);
    row[128 + f]  = f2bf(e1 * sgn);
    row[256 + f]  = f2bf(cm);
    row[384 + f]  = f2bf(cm * sgn);
    row[512 + f]  = f2bf(pr);        // unnormalized; 1/gmax folded into wT(w_rk)
    row[640 + f]  = f2bf(pr * sgn);

    __shared__ float red[128];
    red[f] = pr;
    __syncthreads();
    for (int s = 64; s > 0; s >>= 1) {
        if (f < s) red[f] = fmaxf(red[f], red[f + s]);
        __syncthreads();
    }
    if (f == 0) atomicMax((int*)gmax, __float_as_int(red[0]));
}

// ---------------- all 5 weight transposes in one launch ----------------
__global__ __launch_bounds__(256) void wtrans_all(
    const float* __restrict__ wq, const float* __restrict__ wk, const float* __restrict__ wv,
    const float* __restrict__ wrk, const float* __restrict__ wout,
    u16* __restrict__ tq, u16* __restrict__ tk, u16* __restrict__ tv,
    u16* __restrict__ tr, u16* __restrict__ to, const float* __restrict__ gmax)
{
    const float* W; u16* WT; int scale_from = 1 << 30;
    switch (blockIdx.z) {
        case 0: W = wq;  WT = tq; break;
        case 1: W = wk;  WT = tk; break;
        case 2: W = wv;  WT = tv; break;
        case 3: W = wrk; WT = tr; scale_from = 512; break;
        default: W = wout; WT = to; break;
    }
    __shared__ float t[64][65];
    int k0 = blockIdx.x * 64, n0 = blockIdx.y * 64;
    int tid = threadIdx.x;
    float inv = (scale_from < DM) ? (1.0f / (*gmax)) : 1.0f;

    #pragma unroll
    for (int it = 0; it < 4; ++it) {
        int idx = it * 256 + tid;
        int r = idx >> 4, c4 = (idx & 15) << 2;
        float4 v = *(const float4*)&W[(size_t)(k0 + r) * DM + n0 + c4];
        t[r][c4] = v.x; t[r][c4 + 1] = v.y; t[r][c4 + 2] = v.z; t[r][c4 + 3] = v.w;
    }
    __syncthreads();
    #pragma unroll
    for (int it = 0; it < 4; ++it) {
        int idx = it * 256 + tid;
        int rn = idx >> 4, k4 = (idx & 15) << 2;
        u16x4 o;
        #pragma unroll
        for (int e = 0; e < 4; ++e) {
            float f = t[k4 + e][rn];
            if (k0 + k4 + e >= scale_from) f *= inv;
            o[e] = f2bf(f);
        }
        *(u16x4*)&WT[(size_t)(n0 + rn) * DM + k0 + k4] = o;
    }
}

// ---------------- fused projection GEMMs: q/k/v (f32 A) + rk (bf16 A), head-scatter bf16 out ----
__global__ __launch_bounds__(256) void gemm_all(
    const float* __restrict__ q, const float* __restrict__ k, const float* __restrict__ v,
    const u16* __restrict__ peb,
    const u16* __restrict__ wTq, const u16* __restrict__ wTk, const u16* __restrict__ wTv,
    const u16* __restrict__ wTr,
    u16* __restrict__ qh, u16* __restrict__ kh, u16* __restrict__ vh, u16* __restrict__ rk)
{
    const void* A; const u16* WT; u16* dst; int M; float alpha; bool af32;
    switch (blockIdx.z) {
        case 0: if (blockIdx.x >= 32) return; A = q; WT = wTq; dst = qh; M = S_LEN; alpha = 0.125f; af32 = true; break;
        case 1: if (blockIdx.x >= 32) return; A = k; WT = wTk; dst = kh; M = S_LEN; alpha = 1.0f; af32 = true; break;
        case 2: if (blockIdx.x >= 32) return; A = v; WT = wTv; dst = vh; M = S_LEN; alpha = 1.0f; af32 = true; break;
        default: A = peb; WT = wTr; dst = rk; M = T_LEN; alpha = 1.0f; af32 = false; break;
    }

    __shared__ u16 As[64 * 72];
    __shared__ u16 Ws[64 * 72];
    int tid = threadIdx.x;
    int row0 = blockIdx.x * 64, col0 = blockIdx.y * 64;
    int w = tid >> 6, l = tid & 63, l15 = l & 15, lg = l >> 4;

    f32x4 acc[4];
    #pragma unroll
    for (int cb = 0; cb < 4; ++cb) acc[cb] = (f32x4){0.f, 0.f, 0.f, 0.f};

    for (int k0 = 0; k0 < DM; k0 += 64) {
        __syncthreads();
        #pragma unroll
        for (int it = 0; it < 4; ++it) {
            int idx = it * 256 + tid;
            int r = idx >> 4, c4 = (idx & 15) << 2;
            int gr = row0 + r;
            u16x4 va = {0, 0, 0, 0};
            if (gr < M) {
                if (af32) {
                    float4 vf = *(const float4*)&((const float*)A)[(size_t)gr * DM + k0 + c4];
                    va[0] = f2bf(vf.x); va[1] = f2bf(vf.y); va[2] = f2bf(vf.z); va[3] = f2bf(vf.w);
                } else {
                    va = *(const u16x4*)&((const u16*)A)[(size_t)gr * DM + k0 + c4];
                }
            }
            *(u16x4*)&As[r * 72 + c4] = va;
            *(u16x4*)&Ws[r * 72 + c4] = *(const u16x4*)&WT[(size_t)(col0 + r) * DM + k0 + c4];
        }
        __syncthreads();
        #pragma unroll
        for (int ks = 0; ks < 2; ++ks) {
            int off = ks * 32 + lg * 8;
            s16x8 aF = *(const s16x8*)&As[(w * 16 + l15) * 72 + off];
            #pragma unroll
            for (int cb = 0; cb < 4; ++cb) {
                s16x8 bF = *(const s16x8*)&Ws[(cb * 16 + l15) * 72 + off];
                acc[cb] = __builtin_amdgcn_mfma_f32_16x16x32_bf16(aF, bF, acc[cb], 0, 0, 0);
            }
        }
    }

    #pragma unroll
    for (int cb = 0; cb < 4; ++cb)
        #pragma unroll
        for (int rg = 0; rg < 4; ++rg) {
            int m = row0 + w * 16 + lg * 4 + rg;
            if (m >= M) continue;
            dst[((size_t)blockIdx.y * M + m) * 64 + cb * 16 + l15] = f2bf(acc[cb][rg] * alpha);
        }
}

// ---------------- bf16 MFMA GEMM (out-projection): C_f32 = A_bf16 @ WT^T + bias ----------------
__global__ __launch_bounds__(256) void gemm_out(const u16* __restrict__ A, const u16* __restrict__ WT,
                                                float* __restrict__ C, const float* __restrict__ bias)
{
    __shared__ u16 As[64 * 72];
    __shared__ u16 Ws[64 * 72];
    int tid = threadIdx.x;
    int row0 = blockIdx.x * 64, col0 = blockIdx.y * 64;
    int w = tid >> 6, l = tid & 63, l15 = l & 15, lg = l >> 4;

    f32x4 acc[4];
    #pragma unroll
    for (int cb = 0; cb < 4; ++cb) acc[cb] = (f32x4){0.f, 0.f, 0.f, 0.f};

    for (int k0 = 0; k0 < DM; k0 += 64) {
        __syncthreads();
        #pragma unroll
        for (int it = 0; it < 4; ++it) {
            int idx = it * 256 + tid;
            int r = idx >> 4, c4 = (idx & 15) << 2;
            *(u16x4*)&As[r * 72 + c4] = *(const u16x4*)&A[(size_t)(row0 + r) * DM + k0 + c4];
            *(u16x4*)&Ws[r * 72 + c4] = *(const u16x4*)&WT[(size_t)(col0 + r) * DM + k0 + c4];
        }
        __syncthreads();
        #pragma unroll
        for (int ks = 0; ks < 2; ++ks) {
            int off = ks * 32 + lg * 8;
            s16x8 aF = *(const s16x8*)&As[(w * 16 + l15) * 72 + off];
            #pragma unroll
            for (int cb = 0; cb < 4; ++cb) {
                s16x8 bF = *(const s16x8*)&Ws[(cb * 16 + l15) * 72 + off];
                acc[cb] = __builtin_amdgcn_mfma_f32_16x16x32_bf16(aF, bF, acc[cb], 0, 0, 0);
            }
        }
    }

    #pragma unroll
    for (int cb = 0; cb < 4; ++cb)
        #pragma unroll
        for (int rg = 0; rg < 4; ++rg) {
            int m = row0 + w * 16 + lg * 4 + rg;
            int n = col0 + cb * 16 + l15;
            C[(size_t)m * DM + n] = acc[cb][rg] + bias[n];
        }
}

// ---------------- MFMA fused attention, 32-row blocks, wave j-split ----------------
// block = (32 q-rows, head), grid (64, 12). 4 waves: rg2 = w&1 -> 16-row group,
// jp = w>>1 -> j-half of a 128-j step. Softmax stats merged across jp pairs after
// pass A (associative online-softmax merge); partial PV combined via LDS at end.
#define WAVE_LDS_FENCE() asm volatile("s_waitcnt lgkmcnt(0)" ::: "memory")

__global__ __launch_bounds__(256) void attn_fused(
    const u16* __restrict__ qh, const u16* __restrict__ kh, const u16* __restrict__ vh,
    const u16* __restrict__ rk, const float* __restrict__ rw, const float* __restrict__ rr,
    float* __restrict__ attn, u16* __restrict__ oh)
{
    __shared__ __align__(16) u16 lds_kh[128 * 72];    // kh tile [j][d]; vT [64][136]; comb f32 [2][16][68]
    __shared__ __align__(16) u16 lds_rk[160 * 72];    // rk window [t'][d]
    __shared__ __align__(16) u16 lds_relP[4 * 16 * 80];
    __shared__ float lds_stats[4][16][2];

    const int tid = threadIdx.x;
    const int h  = blockIdx.y;
    const int i0 = blockIdx.x * 32;
    const int w   = tid >> 6;
    const int l   = tid & 63;
    const int l15 = l & 15;
    const int lg  = l >> 4;
    const int rg2 = w & 1;       // row-group
    const int jp  = w >> 1;      // j-parity
    const int pb  = 16 + jp * 64 - rg2 * 16;   // band base in rk window
    const int tb0 = 2016 - i0;                 // Tlo = tb0 + jt

    const u16* qh_h = qh + (size_t)h * S_LEN * DEPTH;
    const u16* kh_h = kh + (size_t)h * S_LEN * DEPTH;
    const u16* vh_h = vh + (size_t)h * S_LEN * DEPTH;
    const u16* rk_h = rk + (size_t)h * T_LEN * DEPTH;
    float* attn_h = attn + ((size_t)h * S_LEN + i0) * S_LEN;

    // A-frags for this wave's 16 rows
    s16x8 qwf[2], qrf[2];
    {
        int arow = i0 + rg2 * 16 + l15;
        #pragma unroll
        for (int ks = 0; ks < 2; ++ks) {
            int bd = ks * 32 + lg * 8;
            s16x8 qv = *(const s16x8*)&qh_h[(size_t)arow * DEPTH + bd];
            #pragma unroll
            for (int e = 0; e < 8; ++e) {
                float f = bf2f((u16)qv[e]);
                qwf[ks][e] = (short)f2bf(f + rw[h * 64 + bd + e]);
                qrf[ks][e] = (short)f2bf(f + rr[h * 64 + bd + e]);
            }
        }
    }

    u16* relw = &lds_relP[w * 16 * 80];
    float run_max[4], run_sum[4];
    #pragma unroll
    for (int rg = 0; rg < 4; ++rg) { run_max[rg] = -3.0e38f; run_sum[rg] = 0.f; }

    // =================== PASS A: stats only ===================
    for (int jt = 0; jt < S_LEN; jt += 128) {
        __syncthreads();
        #pragma unroll
        for (int it = 0; it < 8; ++it) {
            int idx = it * 256 + tid;
            int j = idx >> 4, d4 = (idx & 15) << 2;
            *(u16x4*)&lds_kh[j * 72 + d4] = *(const u16x4*)&kh_h[(size_t)(jt + j) * DEPTH + d4];
        }
        int Tlo = tb0 + jt;
        #pragma unroll
        for (int it = 0; it < 10; ++it) {
            int idx = it * 256 + tid;
            int tr = idx >> 4, d4 = (idx & 15) << 2;
            int t = Tlo + tr;
            u16x4 vv = {0, 0, 0, 0};
            if (t >= 0 && t < T_LEN) vv = *(const u16x4*)&rk_h[(size_t)t * DEPTH + d4];
            *(u16x4*)&lds_rk[tr * 72 + d4] = vv;
        }
        __syncthreads();

        f32x4 accC[4], accR[5];
        #pragma unroll
        for (int cb = 0; cb < 4; ++cb) accC[cb] = (f32x4){0.f, 0.f, 0.f, 0.f};
        #pragma unroll
        for (int tb = 0; tb < 5; ++tb) accR[tb] = (f32x4){0.f, 0.f, 0.f, 0.f};

        #pragma unroll
        for (int ks = 0; ks < 2; ++ks) {
            int off = ks * 32 + lg * 8;
            #pragma unroll
            for (int cb = 0; cb < 4; ++cb) {
                s16x8 b = *(const s16x8*)&lds_kh[(jp * 64 + cb * 16 + l15) * 72 + off];
                accC[cb] = __builtin_amdgcn_mfma_f32_16x16x32_bf16(qwf[ks], b, accC[cb], 0, 0, 0);
            }
            #pragma unroll
            for (int tb = 0; tb < 5; ++tb) {
                s16x8 b = *(const s16x8*)&lds_rk[(pb + tb * 16 + l15) * 72 + off];
                accR[tb] = __builtin_amdgcn_mfma_f32_16x16x32_bf16(qrf[ks], b, accR[tb], 0, 0, 0);
            }
        }
        #pragma unroll
        for (int tb = 0; tb < 5; ++tb)
            #pragma unroll
            for (int rg = 0; rg < 4; ++rg)
                relw[(lg * 4 + rg) * 80 + tb * 16 + l15] = f2bf(accR[tb][rg]);
        WAVE_LDS_FENCE();
        #pragma unroll
        for (int cb = 0; cb < 4; ++cb)
            #pragma unroll
            for (int rg = 0; rg < 4; ++rg) {
                int row = lg * 4 + rg;
                accC[cb][rg] += bf2f(relw[row * 80 + 15 + cb * 16 + l15 - row]);
            }
        #pragma unroll
        for (int rg = 0; rg < 4; ++rg) {
            float m = fmaxf(fmaxf(accC[0][rg], accC[1][rg]), fmaxf(accC[2][rg], accC[3][rg]));
            m = fmaxf(m, __shfl_xor(m, 1));
            m = fmaxf(m, __shfl_xor(m, 2));
            m = fmaxf(m, __shfl_xor(m, 4));
            m = fmaxf(m, __shfl_xor(m, 8));
            float nm = fmaxf(run_max[rg], m);
            float s = __expf(accC[0][rg] - nm) + __expf(accC[1][rg] - nm)
                    + __expf(accC[2][rg] - nm) + __expf(accC[3][rg] - nm);
            s += __shfl_xor(s, 1);
            s += __shfl_xor(s, 2);
            s += __shfl_xor(s, 4);
            s += __shfl_xor(s, 8);
            run_sum[rg] = run_sum[rg] * __expf(run_max[rg] - nm) + s;
            run_max[rg] = nm;
        }
    }

    // ---- merge stats across jp pairs (disjoint j-subsets; associative merge) ----
    if (l15 == 0) {
        #pragma unroll
        for (int rg = 0; rg < 4; ++rg) {
            lds_stats[w][lg * 4 + rg][0] = run_max[rg];
            lds_stats[w][lg * 4 + rg][1] = run_sum[rg];
        }
    }
    __syncthreads();
    {
        int pw = w ^ 2;
        #pragma unroll
        for (int rg = 0; rg < 4; ++rg) {
            float m2 = lds_stats[pw][lg * 4 + rg][0];
            float s2 = lds_stats[pw][lg * 4 + rg][1];
            float nm = fmaxf(run_max[rg], m2);
            run_sum[rg] = run_sum[rg] * __expf(run_max[rg] - nm) + s2 * __expf(m2 - nm);
            run_max[rg] = nm;
        }
    }

    float inv_sum[4];
    #pragma unroll
    for (int rg = 0; rg < 4; ++rg) inv_sum[rg] = 1.0f / run_sum[rg];

    f32x4 accO[4];
    #pragma unroll
    for (int db = 0; db < 4; ++db) accO[db] = (f32x4){0.f, 0.f, 0.f, 0.f};

    // =================== PASS B: attn write + PV ===================
    for (int jt = 0; jt < S_LEN; jt += 128) {
        __syncthreads();
        #pragma unroll
        for (int it = 0; it < 8; ++it) {
            int idx = it * 256 + tid;
            int j = idx >> 4, d4 = (idx & 15) << 2;
            *(u16x4*)&lds_kh[j * 72 + d4] = *(const u16x4*)&kh_h[(size_t)(jt + j) * DEPTH + d4];
        }
        int Tlo = tb0 + jt;
        #pragma unroll
        for (int it = 0; it < 10; ++it) {
            int idx = it * 256 + tid;
            int tr = idx >> 4, d4 = (idx & 15) << 2;
            int t = Tlo + tr;
            u16x4 vv = {0, 0, 0, 0};
            if (t >= 0 && t < T_LEN) vv = *(const u16x4*)&rk_h[(size_t)t * DEPTH + d4];
            *(u16x4*)&lds_rk[tr * 72 + d4] = vv;
        }
        __syncthreads();

        f32x4 accC[4], accR[5];
        #pragma unroll
        for (int cb = 0; cb < 4; ++cb) accC[cb] = (f32x4){0.f, 0.f, 0.f, 0.f};
        #pragma unroll
        for (int tb = 0; tb < 5; ++tb) accR[tb] = (f32x4){0.f, 0.f, 0.f, 0.f};

        #pragma unroll
        for (int ks = 0; ks < 2; ++ks) {
            int off = ks * 32 + lg * 8;
            #pragma unroll
            for (int cb = 0; cb < 4; ++cb) {
                s16x8 b = *(const s16x8*)&lds_kh[(jp * 64 + cb * 16 + l15) * 72 + off];
                accC[cb] = __builtin_amdgcn_mfma_f32_16x16x32_bf16(qwf[ks], b, accC[cb], 0, 0, 0);
            }
            #pragma unroll
            for (int tb = 0; tb < 5; ++tb) {
                s16x8 b = *(const s16x8*)&lds_rk[(pb + tb * 16 + l15) * 72 + off];
                accR[tb] = __builtin_amdgcn_mfma_f32_16x16x32_bf16(qrf[ks], b, accR[tb], 0, 0, 0);
            }
        }
        #pragma unroll
        for (int tb = 0; tb < 5; ++tb)
            #pragma unroll
            for (int rg = 0; rg < 4; ++rg)
                relw[(lg * 4 + rg) * 80 + tb * 16 + l15] = f2bf(accR[tb][rg]);
        WAVE_LDS_FENCE();
        #pragma unroll
        for (int cb = 0; cb < 4; ++cb)
            #pragma unroll
            for (int rg = 0; rg < 4; ++rg) {
                int row = lg * 4 + rg;
                float lgt = accC[cb][rg] + bf2f(relw[row * 80 + 15 + cb * 16 + l15 - row]);
                float pr = __expf(lgt - run_max[rg]) * inv_sum[rg];
                attn_h[(size_t)(rg2 * 16 + row) * S_LEN + jt + jp * 64 + cb * 16 + l15] = pr;
                relw[row * 80 + cb * 16 + l15] = f2bf(pr);
            }
        __syncthreads();   // all waves done with lds_kh (kh tile)
        // stage V transposed: vT[d][j], j in [jt, jt+128), row stride 136
        #pragma unroll
        for (int it = 0; it < 8; ++it) {
            int idx = it * 256 + tid;
            int j = idx & 127, d4 = (idx >> 7) << 2;
            u16x4 vv = *(const u16x4*)&vh_h[(size_t)(jt + j) * DEPTH + d4];
            lds_kh[(d4 + 0) * 136 + j] = vv.x;
            lds_kh[(d4 + 1) * 136 + j] = vv.y;
            lds_kh[(d4 + 2) * 136 + j] = vv.z;
            lds_kh[(d4 + 3) * 136 + j] = vv.w;
        }
        __syncthreads();
        s16x8 pA[2];
        #pragma unroll
        for (int ks = 0; ks < 2; ++ks)
            pA[ks] = *(const s16x8*)&relw[l15 * 80 + ks * 32 + lg * 8];
        #pragma unroll
        for (int ks = 0; ks < 2; ++ks) {
            int off = jp * 64 + ks * 32 + lg * 8;
            #pragma unroll
            for (int db = 0; db < 4; ++db) {
                s16x8 bv = *(const s16x8*)&lds_kh[(db * 16 + l15) * 136 + off];
                accO[db] = __builtin_amdgcn_mfma_f32_16x16x32_bf16(pA[ks], bv, accO[db], 0, 0, 0);
            }
        }
    }

    // ---- combine partial PV across jp pairs, write oh ----
    float* comb = (float*)lds_kh;   // [2][16][68] f32
    __syncthreads();
    if (jp == 1) {
        #pragma unroll
        for (int db = 0; db < 4; ++db)
            #pragma unroll
            for (int rg = 0; rg < 4; ++rg)
                comb[(rg2 * 16 + lg * 4 + rg) * 68 + db * 16 + l15] = accO[db][rg];
    }
    __syncthreads();
    if (jp == 0) {
        #pragma unroll
        for (int db = 0; db < 4; ++db)
            #pragma unroll
            for (int rg = 0; rg < 4; ++rg) {
                float o = accO[db][rg] + comb[(rg2 * 16 + lg * 4 + rg) * 68 + db * 16 + l15];
                oh[(size_t)(i0 + rg2 * 16 + lg * 4 + rg) * DM + h * 64 + db * 16 + l15] = f2bf(o);
            }
    }
}

extern "C" void kernel_launch(void* const* d_in, const int* in_sizes, int n_in,
                              void* d_out, int out_size, void* d_ws, size_t ws_size,
                              hipStream_t stream) {
    const float* q    = (const float*)d_in[0];
    const float* k    = (const float*)d_in[1];
    const float* v    = (const float*)d_in[2];
    const float* wq   = (const float*)d_in[3];
    const float* wk   = (const float*)d_in[4];
    const float* wv   = (const float*)d_in[5];
    const float* w_rk = (const float*)d_in[6];
    const float* r_w  = (const float*)d_in[7];
    const float* r_r  = (const float*)d_in[8];
    const float* w_out= (const float*)d_in[9];
    const float* b_out= (const float*)d_in[10];

    float* outp = (float*)d_out;                       // [2048][768]
    float* attn = outp + (size_t)S_LEN * DM;           // [12][2048][2048]

    if (ws_size < WS_NEEDED_BYTES) {
        hipLaunchKernelGGL(ws_too_small, dim3(1), dim3(1), 0, stream, outp, (float)ws_size);
        return;
    }

    u16* wsb = (u16*)d_ws;
    u16* qh = wsb + QH_OFF;
    u16* kh = wsb + KH_OFF;
    u16* vh = wsb + VH_OFF;
    u16* rk = wsb + RK_OFF;
    u16* oh = wsb + OH_OFF;
    u16* wTo = wsb + WTO_OFF;
    float* gmax = (float*)(wsb + GMAX_OFF);

    u16* scratch = (u16*)attn;                         // dead until attn_fused writes attn
    u16* peb = scratch + PEB_OFF;
    u16* wTq = scratch + WTQ_OFF;
    u16* wTk = scratch + WTK_OFF;
    u16* wTv = scratch + WTV_OFF;
    u16* wTr = scratch + WTR_OFF;

    hipLaunchKernelGGL(init_gmax, dim3(1), dim3(1), 0, stream, gmax);
    hipLaunchKernelGGL(pe_kernel, dim3(T_LEN), dim3(128), 0, stream, peb, gmax);
    hipLaunchKernelGGL(wtrans_all, dim3(12, 12, 5), dim3(256), 0, stream,
                       wq, wk, wv, w_rk, w_out, wTq, wTk, wTv, wTr, wTo, gmax);

    // q/k/v projections + rk GEMM in one launch (head-scatter bf16)
    hipLaunchKernelGGL(gemm_all, dim3(64, 12, 4), dim3(256), 0, stream,
                       q, k, v, peb, wTq, wTk, wTv, wTr, qh, kh, vh, rk);

    // fused MFMA attention (overwrites scratch region with attn probs)
    hipLaunchKernelGGL(attn_fused, dim3(S_LEN / 32, NH), dim3(256), 0, stream,
                       qh, kh, vh, rk, r_w, r_r, attn, oh);

    // output projection + bias (f32)
    hipLaunchKernelGGL(gemm_out, dim3(32, 12), dim3(256), 0, stream, oh, wTo, outp, b_out);
}